// Round 16
// baseline (405.821 us; speedup 1.0000x reference)
//
#include <hip/hip_runtime.h>

#define NUM_SEG 40000
#define BN_EPS 1e-3f

typedef float f4v __attribute__((ext_vector_type(4)));
typedef short bf16x8 __attribute__((ext_vector_type(8)));
typedef float f32x4 __attribute__((ext_vector_type(4)));

// Order-preserving float->uint encoding (for atomicMax over signed floats).
__device__ __forceinline__ unsigned enc_f(float f) {
    unsigned b = __float_as_uint(f);
    return (b & 0x80000000u) ? ~b : (b | 0x80000000u);
}
__device__ __forceinline__ float dec_f(unsigned u) {
    return __uint_as_float((u & 0x80000000u) ? (u ^ 0x80000000u) : ~u);
}
// bf16 round-to-nearest-even
__device__ __forceinline__ unsigned short f2bf(float f) {
    unsigned b = __float_as_uint(f);
    b += 0x7fffu + ((b >> 16) & 1u);
    return (unsigned short)(b >> 16);
}
__device__ __forceinline__ float bf2f(unsigned short u) {
    return __uint_as_float(((unsigned)u) << 16);
}

// ---------------- k_prep: zero segmax + detect int64/int32 + convert unq -> int32 ----------------
__global__ __launch_bounds__(256) void k_prep(const void* __restrict__ unq, int N,
                                              int* __restrict__ unq32,
                                              float4* __restrict__ segz, int nseg4) {
    __shared__ int sflag;
    const int tid = threadIdx.x;
    if (tid < 64) {
        const unsigned int* u = (const unsigned int*)unq;
        int w = ((N / 2) | 1) + 2 * tid;
        unsigned v = (w < N) ? u[w] : 0u;
        unsigned long long b = __ballot(v != 0u);
        if (tid == 0) sflag = (b == 0ull) ? 1 : 0;
    }
    __syncthreads();
    const int flag = sflag;
    const long i = (long)blockIdx.x * 256 + tid;
    if (i < nseg4) segz[i] = make_float4(0.f, 0.f, 0.f, 0.f);   // 0 == enc(-inf)
    if (i < N) unq32[i] = flag ? (int)((const long long*)unq)[i] : ((const int*)unq)[i];
}

// Shared staging + MFMA body: stages A and Wt (bf16 hi/lo, XOR-swizzled) into lds,
// runs the 3-term split MFMA. DETERMINISTIC: kA and kC produce bit-identical acc.
__device__ __forceinline__ void stage_and_mfma(
    const float* __restrict__ in, const float* __restrict__ W,
    char* lds, int tid, long p0, int N, f32x4 (&acc)[2][4]) {
    const int wv = tid >> 6;
    const int l  = tid & 63;
    // --- stage Wt (transposed, split): wave wv covers k rows wv*16..+15; lane l = out-ch n ---
    {
        unsigned short hb[16], lb[16];
        #pragma unroll
        for (int kk = 0; kk < 16; ++kk) {
            float f = W[(wv * 16 + kk) * 64 + l];      // coalesced 256B row per kk
            unsigned short h = f2bf(f);
            hb[kk] = h;
            lb[kk] = f2bf(f - bf2f(h));
        }
        #pragma unroll
        for (int cc = 0; cc < 4; ++cc) {
            int cb = wv * 32 + cc * 8;
            int addr = l * 128 + (cb ^ ((l & 7) << 4));
            *(ushort4*)(lds + 32768 + addr) = make_ushort4(hb[cc*4], hb[cc*4+1], hb[cc*4+2], hb[cc*4+3]);
            *(ushort4*)(lds + 40960 + addr) = make_ushort4(lb[cc*4], lb[cc*4+1], lb[cc*4+2], lb[cc*4+3]);
        }
    }
    // --- stage A (split): 2048 float4 over 8 iters (regular loads: keep lines in L3 for kC) ---
    #pragma unroll
    for (int it = 0; it < 8; ++it) {
        int f = it * 256 + tid;
        int p = f >> 4;
        long gp = p0 + p;
        float4 v = make_float4(0.f, 0.f, 0.f, 0.f);
        if (gp < N) v = ((const float4*)in)[gp * 16 + (f & 15)];
        unsigned short hx = f2bf(v.x), hy = f2bf(v.y), hz = f2bf(v.z), hw = f2bf(v.w);
        int cb = (f & 15) * 8;
        int addr = p * 128 + (cb ^ ((p & 7) << 4));
        *(ushort4*)(lds + addr)         = make_ushort4(hx, hy, hz, hw);
        *(ushort4*)(lds + 16384 + addr) = make_ushort4(f2bf(v.x - bf2f(hx)), f2bf(v.y - bf2f(hy)),
                                                       f2bf(v.z - bf2f(hz)), f2bf(v.w - bf2f(hw)));
    }
    __syncthreads();

    const int lr = l & 15;
    const int lg = l >> 4;
    #pragma unroll
    for (int ks = 0; ks < 2; ++ks) {
        const int cb = ks * 64 + lg * 16;
        bf16x8 ah[2], al[2], bh[4], bl[4];
        #pragma unroll
        for (int mt = 0; mt < 2; ++mt) {
            int r = wv * 32 + mt * 16 + lr;
            int addr = r * 128 + (cb ^ ((r & 7) << 4));
            ah[mt] = *(const bf16x8*)(lds + addr);
            al[mt] = *(const bf16x8*)(lds + 16384 + addr);
        }
        #pragma unroll
        for (int nt = 0; nt < 4; ++nt) {
            int n = nt * 16 + lr;
            int addr = n * 128 + (cb ^ ((n & 7) << 4));
            bh[nt] = *(const bf16x8*)(lds + 32768 + addr);
            bl[nt] = *(const bf16x8*)(lds + 40960 + addr);
        }
        #pragma unroll
        for (int mt = 0; mt < 2; ++mt)
            #pragma unroll
            for (int nt = 0; nt < 4; ++nt) {
                acc[mt][nt] = __builtin_amdgcn_mfma_f32_16x16x32_bf16(ah[mt], bh[nt], acc[mt][nt], 0, 0, 0);
                acc[mt][nt] = __builtin_amdgcn_mfma_f32_16x16x32_bf16(ah[mt], bl[nt], acc[mt][nt], 0, 0, 0);
                acc[mt][nt] = __builtin_amdgcn_mfma_f32_16x16x32_bf16(al[mt], bh[nt], acc[mt][nt], 0, 0, 0);
            }
    }
}

// ---------------- kA: MFMA matmul -> stats partials + segmax over RAW x (no x written) ----------------
__global__ __launch_bounds__(256, 3) void kA_stats(
    const float* __restrict__ in, const float* __restrict__ W,
    const int* __restrict__ unq,
    float* __restrict__ sums, float* __restrict__ sqs,
    unsigned int* __restrict__ segmax, int N, int NBS) {
    __shared__ __align__(16) char lds[49152];
    const int tid = threadIdx.x;
    const int blk = blockIdx.x;
    const long p0 = (long)blk * 128;
    const int wv = tid >> 6;
    const int l  = tid & 63;
    const int lr = l & 15;
    const int lg = l >> 4;

    f32x4 acc[2][4] = {};
    stage_and_mfma(in, W, lds, tid, p0, N, acc);

    // --- stats: channel c = nt*16 + lr ---
    {
        float s[4], q[4];
        #pragma unroll
        for (int nt = 0; nt < 4; ++nt) {
            s[nt] = 0.f; q[nt] = 0.f;
            #pragma unroll
            for (int mt = 0; mt < 2; ++mt)
                #pragma unroll
                for (int r = 0; r < 4; ++r) {
                    float x = acc[mt][nt][r];
                    s[nt] += x; q[nt] += x * x;
                }
        }
        #pragma unroll
        for (int off = 16; off < 64; off <<= 1) {
            #pragma unroll
            for (int nt = 0; nt < 4; ++nt) {
                s[nt] += __shfl_xor(s[nt], off);
                q[nt] += __shfl_xor(q[nt], off);
            }
        }
        if (l < 16) {
            #pragma unroll
            for (int nt = 0; nt < 4; ++nt) {
                int c = nt * 16 + l;
                sums[(long)c * NBS + blk * 4 + wv] = s[nt];
                sqs [(long)c * NBS + blk * 4 + wv] = q[nt];
            }
        }
    }

    // --- restage raw x into xbuf, then per-wave run-compressed segmax ---
    __syncthreads();
    float* xbuf = (float*)lds;
    #pragma unroll
    for (int mt = 0; mt < 2; ++mt)
        #pragma unroll
        for (int nt = 0; nt < 4; ++nt)
            #pragma unroll
            for (int r = 0; r < 4; ++r)
                xbuf[(wv * 32 + mt * 16 + lg * 4 + r) * 68 + nt * 16 + lr] = acc[mt][nt][r];
    __syncthreads();

    const long gbase = p0 + (long)wv * 32;
    if (gbase < N) {
        const int cnt = (int)min((long)32, (long)N - gbase);
        const int myseg = unq[gbase + ((l < cnt) ? l : (cnt - 1))];
        int cur = __shfl(myseg, 0);
        unsigned runmax = 0u;
        for (int r = 0; r < cnt; ++r) {
            int seg = __shfl(myseg, r);
            if (seg != cur) {
                atomicMax(&segmax[(long)cur * 64 + l], runmax);
                cur = seg; runmax = 0u;
            }
            runmax = max(runmax, enc_f(xbuf[(wv * 32 + r) * 68 + l]));
        }
        atomicMax(&segmax[(long)cur * 64 + l], runmax);
    }
}

// ---------------- k2: reduce partials -> scale/shift per channel ----------------
__global__ __launch_bounds__(256) void k2_stats(
    const float* __restrict__ sums, const float* __restrict__ sqs,
    const float* __restrict__ gamma, const float* __restrict__ beta,
    float* __restrict__ ss, int N, int NBS) {
    int c = blockIdx.x;
    int tid = threadIdx.x;
    float s = 0.f, q = 0.f;
    for (int i = tid; i < NBS; i += 256) { s += sums[(long)c * NBS + i]; q += sqs[(long)c * NBS + i]; }
    __shared__ float ls[256], lq[256];
    ls[tid] = s; lq[tid] = q;
    __syncthreads();
    for (int off = 128; off > 0; off >>= 1) {
        if (tid < off) { ls[tid] += ls[tid + off]; lq[tid] += lq[tid + off]; }
        __syncthreads();
    }
    if (tid == 0) {
        float mean = ls[0] / (float)N;
        float var  = lq[0] / (float)N - mean * mean;   // biased, matches jnp.var
        float sc = gamma[c] * rsqrtf(var + BN_EPS);
        float sh = beta[c] - mean * sc;
        ss[c] = sc; ss[64 + c] = sh;
    }
}

// ---------------- kC: recompute x (bit-identical), normalize, write BOTH halves dense ----------------
__global__ __launch_bounds__(256, 3) void kC_final(
    const float* __restrict__ in, const float* __restrict__ W,
    const int* __restrict__ unq,
    const unsigned int* __restrict__ segmax, const float* __restrict__ ss,
    float* __restrict__ out, int N) {
    __shared__ __align__(16) char lds[49152];
    const int tid = threadIdx.x;
    const int blk = blockIdx.x;
    const long p0 = (long)blk * 128;
    const int wv = tid >> 6;
    const int l  = tid & 63;
    const int lr = l & 15;
    const int lg = l >> 4;

    f32x4 acc[2][4] = {};
    stage_and_mfma(in, W, lds, tid, p0, N, acc);

    // normalize in regs, restage y into xbuf
    float scv[4], shv[4];
    #pragma unroll
    for (int nt = 0; nt < 4; ++nt) { scv[nt] = ss[nt * 16 + lr]; shv[nt] = ss[64 + nt * 16 + lr]; }
    __syncthreads();
    float* xbuf = (float*)lds;
    #pragma unroll
    for (int mt = 0; mt < 2; ++mt)
        #pragma unroll
        for (int nt = 0; nt < 4; ++nt)
            #pragma unroll
            for (int r = 0; r < 4; ++r)
                xbuf[(wv * 32 + mt * 16 + lg * 4 + r) * 68 + nt * 16 + lr] =
                    fmaxf(fmaf(acc[mt][nt][r], scv[nt], shv[nt]), 0.f);
    __syncthreads();

    // write full 512B rows dense: 32 lanes per row; q<16 -> y from LDS, q>=16 -> gathered seg-max
    const int q  = tid & 31;          // constant across iters (256 % 32 == 0)
    const int qq = q & 15;
    const float4* ss4 = (const float4*)ss;
    const float4 sc4 = ss4[qq], sh4 = ss4[16 + qq];
    #pragma unroll
    for (int it = 0; it < 16; ++it) {
        int f = it * 256 + tid;
        int p = f >> 5;               // local row
        long gp = p0 + p;
        if (gp >= N) continue;
        f4v v;
        if (q < 16) {
            v = *(const f4v*)&xbuf[p * 68 + qq * 4];
        } else {
            int seg = unq[gp];
            uint4 m4 = ((const uint4*)segmax)[(long)seg * 16 + qq];
            v.x = fmaxf(fmaf(dec_f(m4.x), sc4.x, sh4.x), 0.f);
            v.y = fmaxf(fmaf(dec_f(m4.y), sc4.y, sh4.y), 0.f);
            v.z = fmaxf(fmaf(dec_f(m4.z), sc4.z, sh4.z), 0.f);
            v.w = fmaxf(fmaf(dec_f(m4.w), sc4.w, sh4.w), 0.f);
        }
        __builtin_nontemporal_store(v, (f4v*)out + gp * 32 + q);
    }
}

extern "C" void kernel_launch(void* const* d_in, const int* in_sizes, int n_in,
                              void* d_out, int out_size, void* d_ws, size_t ws_size,
                              hipStream_t stream) {
    const float* in    = (const float*)d_in[0];
    const float* W     = (const float*)d_in[1];
    const float* gamma = (const float*)d_in[2];
    const float* beta  = (const float*)d_in[3];
    const void*  unq   = d_in[4];
    float* out = (float*)d_out;

    const int N   = in_sizes[0] / 64;
    const int NB  = (N + 127) / 128;
    const int NBS = 4 * NB;

    char* ws = (char*)d_ws;
    unsigned int* segmax = (unsigned int*)ws;                    // 10.24 MB (encoded floats)
    size_t off = (size_t)NUM_SEG * 64 * 4;
    float* sums = (float*)(ws + off); off += (size_t)64 * NBS * 4;
    float* sqs  = (float*)(ws + off); off += (size_t)64 * NBS * 4;
    float* ss   = (float*)(ws + off); off += 512;
    int*   unq32= (int*)(ws + off);   off += (size_t)N * 4;

    const int n4 = NUM_SEG * 64 / 4;
    const int gprep = max((N + 255) / 256, (n4 + 255) / 256);
    k_prep<<<gprep, 256, 0, stream>>>(unq, N, unq32, (float4*)segmax, n4);
    kA_stats<<<NB, 256, 0, stream>>>(in, W, unq32, sums, sqs, segmax, N, NBS);
    k2_stats<<<64, 256, 0, stream>>>(sums, sqs, gamma, beta, ss, N, NBS);
    kC_final<<<NB, 256, 0, stream>>>(in, W, unq32, segmax, ss, out, N);
}

// Round 17
// 344.250 us; speedup vs baseline: 1.1789x; 1.1789x over previous
//
#include <hip/hip_runtime.h>

#define NUM_SEG 40000
#define BN_EPS 1e-3f

typedef float f4v __attribute__((ext_vector_type(4)));
typedef short bf16x8 __attribute__((ext_vector_type(8)));
typedef float f32x4 __attribute__((ext_vector_type(4)));

// Order-preserving float->uint encoding (for atomicMax over signed floats).
__device__ __forceinline__ unsigned enc_f(float f) {
    unsigned b = __float_as_uint(f);
    return (b & 0x80000000u) ? ~b : (b | 0x80000000u);
}
__device__ __forceinline__ float dec_f(unsigned u) {
    return __uint_as_float((u & 0x80000000u) ? (u ^ 0x80000000u) : ~u);
}
// bf16 round-to-nearest-even
__device__ __forceinline__ unsigned short f2bf(float f) {
    unsigned b = __float_as_uint(f);
    b += 0x7fffu + ((b >> 16) & 1u);
    return (unsigned short)(b >> 16);
}
__device__ __forceinline__ float bf2f(unsigned short u) {
    return __uint_as_float(((unsigned)u) << 16);
}

// ---------------- k_prep: zero segmax + detect int64/int32 + convert unq -> int32 ----------------
__global__ __launch_bounds__(256) void k_prep(const void* __restrict__ unq, int N,
                                              int* __restrict__ unq32,
                                              float4* __restrict__ segz, int nseg4) {
    __shared__ int sflag;
    const int tid = threadIdx.x;
    if (tid < 64) {
        const unsigned int* u = (const unsigned int*)unq;
        int w = ((N / 2) | 1) + 2 * tid;
        unsigned v = (w < N) ? u[w] : 0u;
        unsigned long long b = __ballot(v != 0u);
        if (tid == 0) sflag = (b == 0ull) ? 1 : 0;
    }
    __syncthreads();
    const int flag = sflag;
    const long i = (long)blockIdx.x * 256 + tid;
    if (i < nseg4) segz[i] = make_float4(0.f, 0.f, 0.f, 0.f);   // 0 == enc(-inf)
    if (i < N) unq32[i] = flag ? (int)((const long long*)unq)[i] : ((const int*)unq)[i];
}

// ---------------- k1: MFMA bf16-split matmul -> raw x to DENSE xtmp, stats, segmax over RAW x ----------------
// 256 thr, 128-pt tile, LDS 48KB -> 3 blocks/CU. x = ahi@Whi + ahi@Wlo + alo@Whi (fp32 acc).
// Cache policy: in = NT loads (never re-read); xtmp = REGULAR stores (L3 retains for k4).
__global__ __launch_bounds__(256, 3) void k1_mfma(
    const float* __restrict__ in, const float* __restrict__ W,
    const int* __restrict__ unq,
    float* __restrict__ xtmp, float* __restrict__ sums, float* __restrict__ sqs,
    unsigned int* __restrict__ segmax, int N, int NBS) {
    __shared__ __align__(16) char lds[49152];
    // bytes [0,16384): Ahi[128][64]bf16 swz   [16384,32768): Alo
    // [32768,40960): Whi_t[64][64]bf16 swz    [40960,49152): Wlo_t
    // overlay after barrier: xbuf = (float*)lds, [128][68] f32
    const int tid = threadIdx.x;
    const int blk = blockIdx.x;
    const long p0 = (long)blk * 128;
    const int wv = tid >> 6;
    const int l  = tid & 63;

    // --- stage Wt (transposed, split): wave wv covers k rows wv*16..+15; lane l = out-ch n ---
    {
        unsigned short hb[16], lb[16];
        #pragma unroll
        for (int kk = 0; kk < 16; ++kk) {
            float f = W[(wv * 16 + kk) * 64 + l];      // coalesced 256B row per kk
            unsigned short h = f2bf(f);
            hb[kk] = h;
            lb[kk] = f2bf(f - bf2f(h));
        }
        #pragma unroll
        for (int cc = 0; cc < 4; ++cc) {
            int cb = wv * 32 + cc * 8;                 // byte col within row
            int addr = l * 128 + (cb ^ ((l & 7) << 4));
            *(ushort4*)(lds + 32768 + addr) = make_ushort4(hb[cc*4], hb[cc*4+1], hb[cc*4+2], hb[cc*4+3]);
            *(ushort4*)(lds + 40960 + addr) = make_ushort4(lb[cc*4], lb[cc*4+1], lb[cc*4+2], lb[cc*4+3]);
        }
    }
    // --- stage A (split): 2048 float4 over 8 iters, NONTEMPORAL (in is never re-read) ---
    #pragma unroll
    for (int it = 0; it < 8; ++it) {
        int f = it * 256 + tid;
        int p = f >> 4;
        long gp = p0 + p;
        f4v v = {0.f, 0.f, 0.f, 0.f};
        if (gp < N) v = __builtin_nontemporal_load(((const f4v*)in) + gp * 16 + (f & 15));
        unsigned short hx = f2bf(v.x), hy = f2bf(v.y), hz = f2bf(v.z), hw = f2bf(v.w);
        int cb = (f & 15) * 8;
        int addr = p * 128 + (cb ^ ((p & 7) << 4));
        *(ushort4*)(lds + addr)         = make_ushort4(hx, hy, hz, hw);
        *(ushort4*)(lds + 16384 + addr) = make_ushort4(f2bf(v.x - bf2f(hx)), f2bf(v.y - bf2f(hy)),
                                                       f2bf(v.z - bf2f(hz)), f2bf(v.w - bf2f(hw)));
    }
    __syncthreads();

    // --- MFMA: wave wv owns points wv*32..+31 (rows), all 64 channels ---
    const int lr = l & 15;
    const int lg = l >> 4;
    f32x4 acc[2][4] = {};
    #pragma unroll
    for (int ks = 0; ks < 2; ++ks) {
        const int cb = ks * 64 + lg * 16;
        bf16x8 ah[2], al[2], bh[4], bl[4];
        #pragma unroll
        for (int mt = 0; mt < 2; ++mt) {
            int r = wv * 32 + mt * 16 + lr;
            int addr = r * 128 + (cb ^ ((r & 7) << 4));
            ah[mt] = *(const bf16x8*)(lds + addr);
            al[mt] = *(const bf16x8*)(lds + 16384 + addr);
        }
        #pragma unroll
        for (int nt = 0; nt < 4; ++nt) {
            int n = nt * 16 + lr;
            int addr = n * 128 + (cb ^ ((n & 7) << 4));
            bh[nt] = *(const bf16x8*)(lds + 32768 + addr);
            bl[nt] = *(const bf16x8*)(lds + 40960 + addr);
        }
        #pragma unroll
        for (int mt = 0; mt < 2; ++mt)
            #pragma unroll
            for (int nt = 0; nt < 4; ++nt) {
                acc[mt][nt] = __builtin_amdgcn_mfma_f32_16x16x32_bf16(ah[mt], bh[nt], acc[mt][nt], 0, 0, 0);
                acc[mt][nt] = __builtin_amdgcn_mfma_f32_16x16x32_bf16(ah[mt], bl[nt], acc[mt][nt], 0, 0, 0);
                acc[mt][nt] = __builtin_amdgcn_mfma_f32_16x16x32_bf16(al[mt], bh[nt], acc[mt][nt], 0, 0, 0);
            }
    }

    // --- stats: channel c = nt*16 + lr; sum over this wave's 32 points ---
    {
        float s[4], q[4];
        #pragma unroll
        for (int nt = 0; nt < 4; ++nt) {
            s[nt] = 0.f; q[nt] = 0.f;
            #pragma unroll
            for (int mt = 0; mt < 2; ++mt)
                #pragma unroll
                for (int r = 0; r < 4; ++r) {
                    float x = acc[mt][nt][r];
                    s[nt] += x; q[nt] += x * x;
                }
        }
        #pragma unroll
        for (int off = 16; off < 64; off <<= 1) {   // sum lanes sharing lr
            #pragma unroll
            for (int nt = 0; nt < 4; ++nt) {
                s[nt] += __shfl_xor(s[nt], off);
                q[nt] += __shfl_xor(q[nt], off);
            }
        }
        if (l < 16) {
            #pragma unroll
            for (int nt = 0; nt < 4; ++nt) {
                int c = nt * 16 + l;
                sums[(long)c * NBS + blk * 4 + wv] = s[nt];
                sqs [(long)c * NBS + blk * 4 + wv] = q[nt];
            }
        }
    }

    // --- restage raw x into xbuf (overlays A/W tiles) ---
    __syncthreads();   // all frag reads done
    float* xbuf = (float*)lds;
    #pragma unroll
    for (int mt = 0; mt < 2; ++mt)
        #pragma unroll
        for (int nt = 0; nt < 4; ++nt)
            #pragma unroll
            for (int r = 0; r < 4; ++r)
                xbuf[(wv * 32 + mt * 16 + lg * 4 + r) * 68 + nt * 16 + lr] = acc[mt][nt][r];
    __syncthreads();

    // --- DENSE store raw x -> xtmp (REGULAR stores: let L3 retain for k4's immediate re-read) ---
    #pragma unroll
    for (int it = 0; it < 8; ++it) {
        int f = it * 256 + tid;
        int p = f >> 4;
        long gp = p0 + p;
        if (gp < N)
            *((f4v*)xtmp + gp * 16 + (f & 15)) = *(const f4v*)&xbuf[p * 68 + (f & 15) * 4];
    }

    // --- per-wave run-compressed segmax over raw x: 32 consecutive points, lane = channel ---
    const long gbase = p0 + (long)wv * 32;
    if (gbase < N) {
        const int cnt = (int)min((long)32, (long)N - gbase);
        const int myseg = unq[gbase + ((l < cnt) ? l : (cnt - 1))];
        int cur = __shfl(myseg, 0);
        unsigned runmax = 0u;
        for (int r = 0; r < cnt; ++r) {
            int seg = __shfl(myseg, r);
            if (seg != cur) {
                atomicMax(&segmax[(long)cur * 64 + l], runmax);
                cur = seg; runmax = 0u;
            }
            runmax = max(runmax, enc_f(xbuf[(wv * 32 + r) * 68 + l]));
        }
        atomicMax(&segmax[(long)cur * 64 + l], runmax);
    }
}

// ---------------- k2: reduce partials -> scale/shift per channel ----------------
__global__ __launch_bounds__(256) void k2_stats(
    const float* __restrict__ sums, const float* __restrict__ sqs,
    const float* __restrict__ gamma, const float* __restrict__ beta,
    float* __restrict__ ss, int N, int NBS) {
    int c = blockIdx.x;
    int tid = threadIdx.x;
    float s = 0.f, q = 0.f;
    for (int i = tid; i < NBS; i += 256) { s += sums[(long)c * NBS + i]; q += sqs[(long)c * NBS + i]; }
    __shared__ float ls[256], lq[256];
    ls[tid] = s; lq[tid] = q;
    __syncthreads();
    for (int off = 128; off > 0; off >>= 1) {
        if (tid < off) { ls[tid] += ls[tid + off]; lq[tid] += lq[tid + off]; }
        __syncthreads();
    }
    if (tid == 0) {
        float mean = ls[0] / (float)N;
        float var  = lq[0] / (float)N - mean * mean;   // biased, matches jnp.var
        float sc = gamma[c] * rsqrtf(var + BN_EPS);
        float sh = beta[c] - mean * sc;
        ss[c] = sc; ss[64 + c] = sh;
    }
}

// ---------------- k4: read dense xtmp (L3-candidate), write BOTH halves of out dense ----------------
__global__ __launch_bounds__(256) void k4_final(
    float* __restrict__ out, const int* __restrict__ unq,
    const float* __restrict__ xtmp,
    const unsigned int* __restrict__ segmax, const float* __restrict__ ss, int N) {
    long t = (long)blockIdx.x * 256 + threadIdx.x;
    long p = t >> 4;
    int qq = (int)(t & 15);
    if (p >= N) return;
    const float4* ss4 = (const float4*)ss;
    float4 sc4 = ss4[qq], sh4 = ss4[16 + qq];

    // left: y = relu(sc*x + sh) from dense xtmp
    f4v x4 = *((const f4v*)xtmp + p * 16 + qq);
    f4v y4;
    y4.x = fmaxf(fmaf(x4.x, sc4.x, sh4.x), 0.f);
    y4.y = fmaxf(fmaf(x4.y, sc4.y, sh4.y), 0.f);
    y4.z = fmaxf(fmaf(x4.z, sc4.z, sh4.z), 0.f);
    y4.w = fmaxf(fmaf(x4.w, sc4.w, sh4.w), 0.f);
    __builtin_nontemporal_store(y4, (f4v*)out + p * 32 + qq);

    // right: decode segmax(raw x), apply same monotone map (exact: same fma as the argmax point)
    int seg = unq[p];
    uint4 m4 = ((const uint4*)segmax)[(long)seg * 16 + qq];
    f4v z4;
    z4.x = fmaxf(fmaf(dec_f(m4.x), sc4.x, sh4.x), 0.f);
    z4.y = fmaxf(fmaf(dec_f(m4.y), sc4.y, sh4.y), 0.f);
    z4.z = fmaxf(fmaf(dec_f(m4.z), sc4.z, sh4.z), 0.f);
    z4.w = fmaxf(fmaf(dec_f(m4.w), sc4.w, sh4.w), 0.f);
    __builtin_nontemporal_store(z4, (f4v*)out + p * 32 + 16 + qq);
}

extern "C" void kernel_launch(void* const* d_in, const int* in_sizes, int n_in,
                              void* d_out, int out_size, void* d_ws, size_t ws_size,
                              hipStream_t stream) {
    const float* in    = (const float*)d_in[0];
    const float* W     = (const float*)d_in[1];
    const float* gamma = (const float*)d_in[2];
    const float* beta  = (const float*)d_in[3];
    const void*  unq   = d_in[4];
    float* out = (float*)d_out;

    const int N   = in_sizes[0] / 64;
    const int NB  = (N + 127) / 128;
    const int NBS = 4 * NB;

    char* ws = (char*)d_ws;
    unsigned int* segmax = (unsigned int*)ws;                    // 10.24 MB (encoded floats)
    size_t off = (size_t)NUM_SEG * 64 * 4;
    float* sums = (float*)(ws + off); off += (size_t)64 * NBS * 4;
    float* sqs  = (float*)(ws + off); off += (size_t)64 * NBS * 4;
    float* ss   = (float*)(ws + off); off += 512;
    int*   unq32= (int*)(ws + off);   off += (size_t)N * 4;
    off = (off + 255) & ~(size_t)255;
    float* xtmp = (float*)(ws + off); off += (size_t)N * 64 * 4; // 256 MB dense raw-x

    const int n4 = NUM_SEG * 64 / 4;
    const int gprep = max((N + 255) / 256, (n4 + 255) / 256);
    k_prep<<<gprep, 256, 0, stream>>>(unq, N, unq32, (float4*)segmax, n4);
    k1_mfma<<<NB, 256, 0, stream>>>(in, W, unq32, xtmp, sums, sqs, segmax, N, NBS);
    k2_stats<<<64, 256, 0, stream>>>(sums, sqs, gamma, beta, ss, N, NBS);
    k4_final<<<(int)(((long)N * 16 + 255) / 256), 256, 0, stream>>>(out, unq32, xtmp, segmax, ss, N);
}

// Round 18
// 324.485 us; speedup vs baseline: 1.2507x; 1.0609x over previous
//
#include <hip/hip_runtime.h>

#define NUM_SEG 40000
#define BN_EPS 1e-3f

typedef float f4v __attribute__((ext_vector_type(4)));
typedef _Float16 f16x8 __attribute__((ext_vector_type(8)));
typedef float f32x4 __attribute__((ext_vector_type(4)));

// Order-preserving float->uint encoding (for atomicMax over signed floats).
__device__ __forceinline__ unsigned enc_f(float f) {
    unsigned b = __float_as_uint(f);
    return (b & 0x80000000u) ? ~b : (b | 0x80000000u);
}
__device__ __forceinline__ float dec_f(unsigned u) {
    return __uint_as_float((u & 0x80000000u) ? (u ^ 0x80000000u) : ~u);
}

// ---------------- k_prep: zero segmax + detect int64/int32 + convert unq -> int32 ----------------
__global__ __launch_bounds__(256) void k_prep(const void* __restrict__ unq, int N,
                                              int* __restrict__ unq32,
                                              float4* __restrict__ segz, int nseg4) {
    __shared__ int sflag;
    const int tid = threadIdx.x;
    if (tid < 64) {
        const unsigned int* u = (const unsigned int*)unq;
        int w = ((N / 2) | 1) + 2 * tid;
        unsigned v = (w < N) ? u[w] : 0u;
        unsigned long long b = __ballot(v != 0u);
        if (tid == 0) sflag = (b == 0ull) ? 1 : 0;
    }
    __syncthreads();
    const int flag = sflag;
    const long i = (long)blockIdx.x * 256 + tid;
    if (i < nseg4) segz[i] = make_float4(0.f, 0.f, 0.f, 0.f);   // 0 == enc(-inf)
    if (i < N) unq32[i] = flag ? (int)((const long long*)unq)[i] : ((const int*)unq)[i];
}

// ---------------- k1: f16 2-term MFMA matmul -> raw x to DENSE xtmp, stats, segmax over RAW x ----------------
// LDS 40KB: A_f32[128][256B] chunk-swizzled (c^=(r&15)) at 0; W16_t[64][128B] (c^=(n&7)) at 32768.
// 4 blocks/CU * 4 waves = 16 waves/CU. x = ahi@W16 + alo@W16 (A-split exact; W f16 err ~2^-11).
// A staging = pure f32 copy (no conversion VALU); hi/lo extracted at frag-read time.
__global__ __launch_bounds__(256, 4) void k1_mfma(
    const float* __restrict__ in, const float* __restrict__ W,
    const int* __restrict__ unq,
    float* __restrict__ xtmp, float* __restrict__ sums, float* __restrict__ sqs,
    unsigned int* __restrict__ segmax, int N, int NBS) {
    __shared__ __align__(16) char lds[40960];
    // overlay after barrier: xbuf = (float*)lds, [128][68] f32 (34.8KB <= 40KB)
    const int tid = threadIdx.x;
    const int blk = blockIdx.x;
    const long p0 = (long)blk * 128;
    const int wv = tid >> 6;
    const int l  = tid & 63;

    // --- stage W16_t: wave wv covers k in [wv*16, +16); lane l = out-ch n ---
    {
        _Float16 h[16];
        #pragma unroll
        for (int kk = 0; kk < 16; ++kk)
            h[kk] = (_Float16)W[(wv * 16 + kk) * 64 + l];   // coalesced 256B row per kk
        f16x8 c0 = { h[0], h[1], h[2], h[3], h[4], h[5], h[6], h[7] };
        f16x8 c1 = { h[8], h[9], h[10], h[11], h[12], h[13], h[14], h[15] };
        int base = 32768 + l * 128;
        *(f16x8*)(lds + base + (((wv * 2)     ^ (l & 7)) << 4)) = c0;
        *(f16x8*)(lds + base + (((wv * 2 + 1) ^ (l & 7)) << 4)) = c1;
    }
    // --- stage A as raw f32 copy (2048 float4 over 8 iters; swizzled LDS chunk) ---
    #pragma unroll
    for (int it = 0; it < 8; ++it) {
        int f = it * 256 + tid;
        int r = f >> 4, c = f & 15;
        long gp = p0 + r;
        f4v v = {0.f, 0.f, 0.f, 0.f};
        if (gp < N) v = *((const f4v*)in + gp * 16 + c);
        *(f4v*)(lds + r * 256 + ((c ^ (r & 15)) << 4)) = v;
    }
    __syncthreads();

    // --- MFMA: wave wv owns rows [wv*32, +32), all 64 channels ---
    const int lr = l & 15;
    const int lg = l >> 4;
    f32x4 acc[2][4] = {};
    #pragma unroll
    for (int ks = 0; ks < 2; ++ks) {
        f16x8 ah[2], al[2], bh[4];
        #pragma unroll
        for (int mt = 0; mt < 2; ++mt) {
            int r = wv * 32 + mt * 16 + lr;
            int cg = ks * 8 + lg * 2;                       // 16B f32 chunk index
            f4v a0 = *(const f4v*)(lds + r * 256 + (((cg)     ^ (r & 15)) << 4));
            f4v a1 = *(const f4v*)(lds + r * 256 + (((cg + 1) ^ (r & 15)) << 4));
            float av[8] = { a0.x, a0.y, a0.z, a0.w, a1.x, a1.y, a1.z, a1.w };
            #pragma unroll
            for (int j = 0; j < 8; ++j) {
                _Float16 h = (_Float16)av[j];
                ah[mt][j] = h;
                al[mt][j] = (_Float16)(av[j] - (float)h);
            }
        }
        #pragma unroll
        for (int nt = 0; nt < 4; ++nt) {
            int n = nt * 16 + lr;
            int cg = ks * 4 + lg;                           // 16B f16 chunk index
            bh[nt] = *(const f16x8*)(lds + 32768 + n * 128 + ((cg ^ (n & 7)) << 4));
        }
        #pragma unroll
        for (int mt = 0; mt < 2; ++mt)
            #pragma unroll
            for (int nt = 0; nt < 4; ++nt) {
                acc[mt][nt] = __builtin_amdgcn_mfma_f32_16x16x32_f16(ah[mt], bh[nt], acc[mt][nt], 0, 0, 0);
                acc[mt][nt] = __builtin_amdgcn_mfma_f32_16x16x32_f16(al[mt], bh[nt], acc[mt][nt], 0, 0, 0);
            }
    }

    // --- stats: channel c = nt*16 + lr; sum over this wave's 32 points ---
    {
        float s[4], q[4];
        #pragma unroll
        for (int nt = 0; nt < 4; ++nt) {
            s[nt] = 0.f; q[nt] = 0.f;
            #pragma unroll
            for (int mt = 0; mt < 2; ++mt)
                #pragma unroll
                for (int r = 0; r < 4; ++r) {
                    float x = acc[mt][nt][r];
                    s[nt] += x; q[nt] += x * x;
                }
        }
        #pragma unroll
        for (int off = 16; off < 64; off <<= 1) {   // sum lanes sharing lr
            #pragma unroll
            for (int nt = 0; nt < 4; ++nt) {
                s[nt] += __shfl_xor(s[nt], off);
                q[nt] += __shfl_xor(q[nt], off);
            }
        }
        if (l < 16) {
            #pragma unroll
            for (int nt = 0; nt < 4; ++nt) {
                int c = nt * 16 + l;
                sums[(long)c * NBS + blk * 4 + wv] = s[nt];
                sqs [(long)c * NBS + blk * 4 + wv] = q[nt];
            }
        }
    }

    // --- restage raw x into xbuf (overlays staging tiles) ---
    __syncthreads();   // all frag reads done
    float* xbuf = (float*)lds;
    #pragma unroll
    for (int mt = 0; mt < 2; ++mt)
        #pragma unroll
        for (int nt = 0; nt < 4; ++nt)
            #pragma unroll
            for (int r = 0; r < 4; ++r)
                xbuf[(wv * 32 + mt * 16 + lg * 4 + r) * 68 + nt * 16 + lr] = acc[mt][nt][r];
    __syncthreads();

    // --- DENSE store raw x -> xtmp (regular stores; L3 may retain for k4) ---
    #pragma unroll
    for (int it = 0; it < 8; ++it) {
        int f = it * 256 + tid;
        int p = f >> 4;
        long gp = p0 + p;
        if (gp < N)
            *((f4v*)xtmp + gp * 16 + (f & 15)) = *(const f4v*)&xbuf[p * 68 + (f & 15) * 4];
    }

    // --- per-wave run-compressed segmax over raw x: 32 consecutive points, lane = channel ---
    const long gbase = p0 + (long)wv * 32;
    if (gbase < N) {
        const int cnt = (int)min((long)32, (long)N - gbase);
        const int myseg = unq[gbase + ((l < cnt) ? l : (cnt - 1))];
        int cur = __shfl(myseg, 0);
        unsigned runmax = 0u;
        for (int r = 0; r < cnt; ++r) {
            int seg = __shfl(myseg, r);
            if (seg != cur) {
                atomicMax(&segmax[(long)cur * 64 + l], runmax);
                cur = seg; runmax = 0u;
            }
            runmax = max(runmax, enc_f(xbuf[(wv * 32 + r) * 68 + l]));
        }
        atomicMax(&segmax[(long)cur * 64 + l], runmax);
    }
}

// ---------------- k2: reduce partials -> scale/shift per channel ----------------
__global__ __launch_bounds__(256) void k2_stats(
    const float* __restrict__ sums, const float* __restrict__ sqs,
    const float* __restrict__ gamma, const float* __restrict__ beta,
    float* __restrict__ ss, int N, int NBS) {
    int c = blockIdx.x;
    int tid = threadIdx.x;
    float s = 0.f, q = 0.f;
    for (int i = tid; i < NBS; i += 256) { s += sums[(long)c * NBS + i]; q += sqs[(long)c * NBS + i]; }
    __shared__ float ls[256], lq[256];
    ls[tid] = s; lq[tid] = q;
    __syncthreads();
    for (int off = 128; off > 0; off >>= 1) {
        if (tid < off) { ls[tid] += ls[tid + off]; lq[tid] += lq[tid + off]; }
        __syncthreads();
    }
    if (tid == 0) {
        float mean = ls[0] / (float)N;
        float var  = lq[0] / (float)N - mean * mean;   // biased, matches jnp.var
        float sc = gamma[c] * rsqrtf(var + BN_EPS);
        float sh = beta[c] - mean * sc;
        ss[c] = sc; ss[64 + c] = sh;
    }
}

// ---------------- k4: read dense xtmp, write BOTH halves of out dense ----------------
__global__ __launch_bounds__(256) void k4_final(
    float* __restrict__ out, const int* __restrict__ unq,
    const float* __restrict__ xtmp,
    const unsigned int* __restrict__ segmax, const float* __restrict__ ss, int N) {
    long t = (long)blockIdx.x * 256 + threadIdx.x;
    long p = t >> 4;
    int qq = (int)(t & 15);
    if (p >= N) return;
    const float4* ss4 = (const float4*)ss;
    float4 sc4 = ss4[qq], sh4 = ss4[16 + qq];

    // left: y = relu(sc*x + sh) from dense xtmp
    f4v x4 = *((const f4v*)xtmp + p * 16 + qq);
    f4v y4;
    y4.x = fmaxf(fmaf(x4.x, sc4.x, sh4.x), 0.f);
    y4.y = fmaxf(fmaf(x4.y, sc4.y, sh4.y), 0.f);
    y4.z = fmaxf(fmaf(x4.z, sc4.z, sh4.z), 0.f);
    y4.w = fmaxf(fmaf(x4.w, sc4.w, sh4.w), 0.f);
    __builtin_nontemporal_store(y4, (f4v*)out + p * 32 + qq);

    // right: decode segmax(raw x), apply same monotone map (exact: same fma as the argmax point)
    int seg = unq[p];
    uint4 m4 = ((const uint4*)segmax)[(long)seg * 16 + qq];
    f4v z4;
    z4.x = fmaxf(fmaf(dec_f(m4.x), sc4.x, sh4.x), 0.f);
    z4.y = fmaxf(fmaf(dec_f(m4.y), sc4.y, sh4.y), 0.f);
    z4.z = fmaxf(fmaf(dec_f(m4.z), sc4.z, sh4.z), 0.f);
    z4.w = fmaxf(fmaf(dec_f(m4.w), sc4.w, sh4.w), 0.f);
    __builtin_nontemporal_store(z4, (f4v*)out + p * 32 + 16 + qq);
}

extern "C" void kernel_launch(void* const* d_in, const int* in_sizes, int n_in,
                              void* d_out, int out_size, void* d_ws, size_t ws_size,
                              hipStream_t stream) {
    const float* in    = (const float*)d_in[0];
    const float* W     = (const float*)d_in[1];
    const float* gamma = (const float*)d_in[2];
    const float* beta  = (const float*)d_in[3];
    const void*  unq   = d_in[4];
    float* out = (float*)d_out;

    const int N   = in_sizes[0] / 64;
    const int NB  = (N + 127) / 128;
    const int NBS = 4 * NB;

    char* ws = (char*)d_ws;
    unsigned int* segmax = (unsigned int*)ws;                    // 10.24 MB (encoded floats)
    size_t off = (size_t)NUM_SEG * 64 * 4;
    float* sums = (float*)(ws + off); off += (size_t)64 * NBS * 4;
    float* sqs  = (float*)(ws + off); off += (size_t)64 * NBS * 4;
    float* ss   = (float*)(ws + off); off += 512;
    int*   unq32= (int*)(ws + off);   off += (size_t)N * 4;
    off = (off + 255) & ~(size_t)255;
    float* xtmp = (float*)(ws + off); off += (size_t)N * 64 * 4; // 256 MB dense raw-x

    const int n4 = NUM_SEG * 64 / 4;
    const int gprep = max((N + 255) / 256, (n4 + 255) / 256);
    k_prep<<<gprep, 256, 0, stream>>>(unq, N, unq32, (float4*)segmax, n4);
    k1_mfma<<<NB, 256, 0, stream>>>(in, W, unq32, xtmp, sums, sqs, segmax, N, NBS);
    k2_stats<<<64, 256, 0, stream>>>(sums, sqs, gamma, beta, ss, N, NBS);
    k4_final<<<(int)(((long)N * 16 + 255) / 256), 256, 0, stream>>>(out, unq32, xtmp, segmax, ss, N);
}